// Round 3
// baseline (730.650 us; speedup 1.0000x reference)
//
#include <hip/hip_runtime.h>

#define BB 256
#define LL 512
#define DD 768
#define CC 19
#define ES 20            // padded class stride
#define IMPOSSIBLE -10000.0f

// ---------------------------------------------------------------------------
// Kernel 1: emissions GEMM.  emis[row][c] = feats[row]·W[c] + bias[c]
// 512 blocks x 256 threads, ONE row per thread (round-0 config: 2 blocks/CU
// -> 64 KB of global loads in flight per CU, vs 32 KB for the 2-row version;
// HBM saturation needs ~22 KB/CU at ~900 cyc latency).  W lives in LDS;
// per-(kc,c) reads are wave-uniform same-address broadcasts (conflict-free).
// A/B vs round-2's 256x2-row version isolates the GEMM config delta.
// ---------------------------------------------------------------------------
__global__ __launch_bounds__(256) void emis_gemm(
    const float* __restrict__ feats,   // [B*L][D]
    const float* __restrict__ W,       // [C][D]
    const float* __restrict__ bias,    // [C]
    float* __restrict__ emis)          // [B*L][ES]
{
    __shared__ float Wl[CC * DD];      // 58368 B (2 blocks/CU fit: 117 KB < 160)
    const int tid = threadIdx.x;

    // cooperative W load: 14592 floats = 57 * 256, coalesced
#pragma unroll
    for (int i = 0; i < 57; ++i)
        Wl[i * 256 + tid] = W[i * 256 + tid];
    __syncthreads();

    const int row = blockIdx.x * 256 + tid;
    const float4* fv = reinterpret_cast<const float4*>(feats + (size_t)row * DD);

    float acc[ES];
#pragma unroll
    for (int c = 0; c < CC; ++c) acc[c] = bias[c];
    acc[19] = 0.0f;

    float4 a0 = fv[0], a1 = fv[1], a2 = fv[2], a3 = fv[3];
    for (int kc = 0; kc < DD / 16; ++kc) {
        const int nk = (kc < DD / 16 - 1) ? kc + 1 : kc;
        float4 n0 = fv[nk * 4 + 0];
        float4 n1 = fv[nk * 4 + 1];
        float4 n2 = fv[nk * 4 + 2];
        float4 n3 = fv[nk * 4 + 3];
#pragma unroll
        for (int c = 0; c < CC; ++c) {
            const float4* wv = reinterpret_cast<const float4*>(&Wl[c * DD + kc * 16]);
            float4 w0 = wv[0], w1 = wv[1], w2 = wv[2], w3 = wv[3];
            float d0 = a0.x * w0.x + a0.y * w0.y + a0.z * w0.z + a0.w * w0.w;
            float d1 = a1.x * w1.x + a1.y * w1.y + a1.z * w1.z + a1.w * w1.w;
            float d2 = a2.x * w2.x + a2.y * w2.y + a2.z * w2.z + a2.w * w2.w;
            float d3 = a3.x * w3.x + a3.y * w3.y + a3.z * w3.z + a3.w * w3.w;
            acc[c] += (d0 + d1) + (d2 + d3);
        }
        a0 = n0; a1 = n1; a2 = n2; a3 = n3;
    }

    float4* ed = reinterpret_cast<float4*>(emis + (size_t)row * ES);
#pragma unroll
    for (int q = 0; q < 5; ++q)
        ed[q] = make_float4(acc[4 * q + 0], acc[4 * q + 1],
                            acc[4 * q + 2], acc[4 * q + 3]);
}

// single-instruction 3-input max (exact same result as fmaxf chain for
// finite inputs; association doesn't change the max) -> shorter tree,
// 9 instr instead of 18 and depth 3 instead of 5 on the critical path.
__device__ inline float max3f(float a, float b, float c) {
    float d;
    asm("v_max3_f32 %0, %1, %2, %3" : "=v"(d) : "v"(a), "v"(b), "v"(c));
    return d;
}

// ---------------------------------------------------------------------------
// Kernel 2: Viterbi scan + parallel backtrack.  256 blocks x 64 threads
// (one wave per batch).  lane = class for the scan; segment-parallel
// function-composition backtrack (64 segments x 8 steps).
// BYTE-IDENTICAL to round 2 (isolating the GEMM A/B this round).
// ---------------------------------------------------------------------------
__global__ __launch_bounds__(64) void scan_bt(
    const float* __restrict__ emis,    // [B*L][ES]
    const float* __restrict__ masks,   // [B][L]
    const float* __restrict__ trans,   // [C][C]
    float* __restrict__ out)           // [B] ++ [B][L]
{
    __shared__ float elds[LL * ES];            // 40960 B
    __shared__ float mlds[LL];                 //  2048 B
    __shared__ unsigned char bp8[LL * ES];     // 10240 B
    __shared__ unsigned char Hl[64 * ES];      //  1280 B
    __shared__ unsigned char vseg[64];
    __shared__ float fbuf[CC];

    const int lane = threadIdx.x;
    const int b    = blockIdx.x;

    // stage emissions (512*20 floats = 2560 float4) and masks, coalesced
    {
        const float4* src = reinterpret_cast<const float4*>(emis + (size_t)b * LL * ES);
        float4* dst = reinterpret_cast<float4*>(elds);
#pragma unroll
        for (int i = 0; i < 40; ++i) dst[i * 64 + lane] = src[i * 64 + lane];
        const float4* ms = reinterpret_cast<const float4*>(masks + b * LL);
        float4* md = reinterpret_cast<float4*>(mlds);
        md[lane] = ms[lane];
        md[64 + lane] = ms[64 + lane];
    }
    __syncthreads();

    // ---------------- scan: lane = class ----------------
    const int ccl = (lane < CC) ? lane : (CC - 1);
    float T[CC];
#pragma unroll
    for (int p = 0; p < CC; ++p) T[p] = trans[ccl * CC + p];
    const float Tstop = trans[(CC - 1) * CC + ccl];

    float s = (lane == CC - 2) ? 0.0f : IMPOSSIBLE;

    float e  = elds[ccl];
    bool  mv = mlds[0] > 0.0f;         // compare hoisted off the critical path
    for (int t = 0; t < LL; ++t) {
        const int tn = (t < LL - 1) ? t + 1 : t;
        float e_n  = elds[tn * ES + ccl];
        bool  mv_n = mlds[tn] > 0.0f;

        float cand[CC];
#pragma unroll
        for (int p = 0; p < CC; ++p) {
            int spi = __builtin_amdgcn_readlane(__builtin_bit_cast(int, s), p);
            cand[p] = __builtin_bit_cast(float, spi) + T[p];
        }
        float t0 = max3f(cand[0],  cand[1],  cand[2]);
        float t1 = max3f(cand[3],  cand[4],  cand[5]);
        float t2 = max3f(cand[6],  cand[7],  cand[8]);
        float t3 = max3f(cand[9],  cand[10], cand[11]);
        float t4 = max3f(cand[12], cand[13], cand[14]);
        float t5 = max3f(cand[15], cand[16], cand[17]);
        float u0 = max3f(t0, t1, t2);
        float u1 = max3f(t3, t4, t5);
        float mx = max3f(u0, u1, cand[18]);

        // first-match argmax (exact reference tie-break: smallest p)
        int arg = CC - 1;
#pragma unroll
        for (int p = CC - 2; p >= 0; --p) arg = (cand[p] == mx) ? p : arg;

        float a = mx + e;
        s = mv ? a : s;                // exact: mask is 0.0f or 1.0f
        if (lane < CC) bp8[t * ES + lane] = (unsigned char)arg;

        e = e_n; mv = mv_n;
    }

    float fin = s + Tstop;
    if (lane < CC) fbuf[lane] = fin;
    __syncthreads();

    // ---------------- final argmax (redundant on all lanes) ----------------
    float best = fbuf[0];
    int   btag = 0;
#pragma unroll
    for (int c = 1; c < CC; ++c) {
        float v = fbuf[c];
        if (v > best) { best = v; btag = c; }
    }
    if (lane == 0) out[b] = best;

    // ---------------- segment transfer tables: lane i covers t in [i*8, i*8+8) ----
    {
        const int base = lane * 8;
        float mj[8];
#pragma unroll
        for (int j = 0; j < 8; ++j) mj[j] = mlds[base + j];
#pragma unroll
        for (int c = 0; c < CC; ++c) {
            int x = c;
#pragma unroll
            for (int j = 7; j >= 0; --j) {
                int nx = bp8[(base + j) * ES + x];
                x = (mj[j] > 0.0f) ? nx : x;
            }
            Hl[lane * ES + c] = (unsigned char)x;
        }
    }
    __syncthreads();

    // ---------------- scalar chain of segment-entry values ----------------
    if (lane == 0) {
        int v = btag;
        vseg[63] = (unsigned char)v;
        for (int i = 62; i >= 0; --i) {
            v = Hl[(i + 1) * ES + v];
            vseg[i] = (unsigned char)v;
        }
    }
    __syncthreads();

    // ---------------- fill 8 tags per lane, store as 2x float4 ----------------
    {
        const int base = lane * 8;
        int cur = vseg[lane];
        float tg[8];
#pragma unroll
        for (int j = 7; j >= 0; --j) {
            bool valid = mlds[base + j] > 0.0f;
            tg[j] = (float)(valid ? cur : -1);
            int nx = bp8[(base + j) * ES + cur];
            cur = valid ? nx : cur;
        }
        float4* pout = reinterpret_cast<float4*>(out + BB + (size_t)b * LL + base);
        pout[0] = make_float4(tg[0], tg[1], tg[2], tg[3]);
        pout[1] = make_float4(tg[4], tg[5], tg[6], tg[7]);
    }
}

extern "C" void kernel_launch(void* const* d_in, const int* in_sizes, int n_in,
                              void* d_out, int out_size, void* d_ws, size_t ws_size,
                              hipStream_t stream) {
    const float* feats = (const float*)d_in[0];
    const float* masks = (const float*)d_in[1];
    const float* W     = (const float*)d_in[2];
    const float* bias  = (const float*)d_in[3];
    const float* trans = (const float*)d_in[4];
    float* out  = (float*)d_out;
    float* emis = (float*)d_ws;        // 131072 * 20 * 4 = 10.5 MB scratch

    emis_gemm<<<dim3(512), dim3(256), 0, stream>>>(feats, W, bias, emis);
    scan_bt<<<dim3(BB), dim3(64), 0, stream>>>(emis, masks, trans, out);
}

// Round 4
// 706.499 us; speedup vs baseline: 1.0342x; 1.0342x over previous
//
#include <hip/hip_runtime.h>

#define BB 256
#define LL 512
#define DD 768
#define CC 19
#define ES 20            // padded class stride
#define IMPOSSIBLE -10000.0f

// single-instruction 3-input max (exact: max is associative for finite floats)
__device__ inline float max3f(float a, float b, float c) {
    float d;
    asm("v_max3_f32 %0, %1, %2, %3" : "=v"(d) : "v"(a), "v"(b), "v"(c));
    return d;
}

// ---------------------------------------------------------------------------
// Fused CRF kernel: 256 blocks (one per batch) x 256 threads (4 waves).
// Phase 1 (all 4 waves): emissions GEMM for this batch's 512 rows, written
//   to LDS (never to global) -- structurally identical to the round-2 proven
//   2-row/thread config (256 blocks x 256 threads, W broadcast from LDS).
// Phase 2 (wave 0): Viterbi scan (lane = class) with t=0 peeled and
//   predecessors p=17 (start, unreachable for t>=1) and p=18 (stop column =
//   IMPOSSIBLE) pruned from the max/argmax -- exact by ~1e4 margin.
// Phase 3 (wave 0): segment-parallel function-composition backtrack.
// No d_ws usage at all.
// ---------------------------------------------------------------------------
__global__ __launch_bounds__(256) void crf_fused(
    const float* __restrict__ feats,   // [B*L][D]
    const float* __restrict__ masks,   // [B][L]
    const float* __restrict__ W,       // [C][D]
    const float* __restrict__ bias,    // [C]
    const float* __restrict__ trans,   // [C][C]
    float* __restrict__ out)           // [B] ++ [B][L]
{
    __shared__ float Wl[CC * DD];              // 58368 B
    __shared__ float elds[LL * ES];            // 40960 B
    __shared__ float mlds[LL];                 //  2048 B
    __shared__ unsigned char bp8[LL * ES];     // 10240 B
    __shared__ unsigned char Hl[64 * ES];      //  1280 B
    __shared__ unsigned char vseg[64];
    __shared__ float fbuf[CC];                 // total ~113 KB -> 1 block/CU

    const int tid = threadIdx.x;
    const int b   = blockIdx.x;

    // ---- phase 1a: cooperative W -> LDS (57*256 floats), masks -> LDS ----
#pragma unroll
    for (int i = 0; i < 57; ++i)
        Wl[i * 256 + tid] = W[i * 256 + tid];
    if (tid < 128) {   // 512 mask floats = 128 float4
        const float4* ms = reinterpret_cast<const float4*>(masks + (size_t)b * LL);
        reinterpret_cast<float4*>(mlds)[tid] = ms[tid];
    }

    // ---- phase 1b: emissions for rows tid and tid+256 of this batch ----
    const int r0 = tid, r1 = tid + 256;
    const float4* f0 = reinterpret_cast<const float4*>(feats + ((size_t)b * LL + r0) * DD);
    const float4* f1 = reinterpret_cast<const float4*>(feats + ((size_t)b * LL + r1) * DD);

    float accA[ES], accB[ES];
#pragma unroll
    for (int c = 0; c < CC; ++c) { float bb = bias[c]; accA[c] = bb; accB[c] = bb; }
    accA[19] = 0.0f; accB[19] = 0.0f;

    // issue first feats loads BEFORE the barrier so HBM latency hides under it
    float4 a0 = f0[0], a1 = f0[1], a2 = f0[2], a3 = f0[3];
    float4 b0 = f1[0], b1 = f1[1], b2 = f1[2], b3 = f1[3];
    __syncthreads();   // Wl + mlds ready

    for (int kc = 0; kc < DD / 16; ++kc) {
        const int nk = (kc < DD / 16 - 1) ? kc + 1 : kc;
        float4 na0 = f0[nk * 4 + 0], na1 = f0[nk * 4 + 1];
        float4 na2 = f0[nk * 4 + 2], na3 = f0[nk * 4 + 3];
        float4 nb0 = f1[nk * 4 + 0], nb1 = f1[nk * 4 + 1];
        float4 nb2 = f1[nk * 4 + 2], nb3 = f1[nk * 4 + 3];
#pragma unroll
        for (int c = 0; c < CC; ++c) {
            const float4* wv = reinterpret_cast<const float4*>(&Wl[c * DD + kc * 16]);
            float4 w0 = wv[0], w1 = wv[1], w2 = wv[2], w3 = wv[3];
            float dA0 = a0.x * w0.x + a0.y * w0.y + a0.z * w0.z + a0.w * w0.w;
            float dA1 = a1.x * w1.x + a1.y * w1.y + a1.z * w1.z + a1.w * w1.w;
            float dA2 = a2.x * w2.x + a2.y * w2.y + a2.z * w2.z + a2.w * w2.w;
            float dA3 = a3.x * w3.x + a3.y * w3.y + a3.z * w3.z + a3.w * w3.w;
            accA[c] += (dA0 + dA1) + (dA2 + dA3);
            float dB0 = b0.x * w0.x + b0.y * w0.y + b0.z * w0.z + b0.w * w0.w;
            float dB1 = b1.x * w1.x + b1.y * w1.y + b1.z * w1.z + b1.w * w1.w;
            float dB2 = b2.x * w2.x + b2.y * w2.y + b2.z * w2.z + b2.w * w2.w;
            float dB3 = b3.x * w3.x + b3.y * w3.y + b3.z * w3.z + b3.w * w3.w;
            accB[c] += (dB0 + dB1) + (dB2 + dB3);
        }
        a0 = na0; a1 = na1; a2 = na2; a3 = na3;
        b0 = nb0; b1 = nb1; b2 = nb2; b3 = nb3;
    }

    {
        float4* eA = reinterpret_cast<float4*>(&elds[r0 * ES]);
        float4* eB = reinterpret_cast<float4*>(&elds[r1 * ES]);
#pragma unroll
        for (int q = 0; q < 5; ++q) {
            eA[q] = make_float4(accA[4 * q + 0], accA[4 * q + 1],
                                accA[4 * q + 2], accA[4 * q + 3]);
            eB[q] = make_float4(accB[4 * q + 0], accB[4 * q + 1],
                                accB[4 * q + 2], accB[4 * q + 3]);
        }
    }
    __syncthreads();   // emissions ready in LDS

    // ---- phase 2: Viterbi scan on wave 0 (lane = class) ----
    if (tid < 64) {
        const int lane = tid;
        const int ccl  = (lane < CC) ? lane : (CC - 1);
        float T[CC];
#pragma unroll
        for (int p = 0; p < CC; ++p) T[p] = trans[ccl * CC + p];
        const float Tstop = trans[(CC - 1) * CC + ccl];

        // peel t=0: init has only class 17 (=start) finite, so bp[0][c]=17
        // (unique max by ~1e4) and s[c] = trans[c][17] + e0[c] when masked in.
        const float sinit = (lane == CC - 2) ? 0.0f : IMPOSSIBLE;
        float e0  = elds[ccl];
        bool  mv0 = mlds[0] > 0.0f;
        float s   = mv0 ? (T[17] + e0) : sinit;
        if (lane < CC) bp8[lane] = (unsigned char)17;

        float e  = elds[ES + ccl];
        bool  mv = mlds[1] > 0.0f;
        for (int t = 1; t < LL; ++t) {
            const int tn = (t < LL - 1) ? t + 1 : t;
            float e_n  = elds[tn * ES + ccl];
            bool  mv_n = mlds[tn] > 0.0f;

            // predecessors p=0..16 only: p=17 has s~-1e4 for t>=1, p=18 has
            // T[c][18]=IMPOSSIBLE -- neither can win (margin ~1e4 vs value
            // spread of a few units).
            float cand[17];
#pragma unroll
            for (int p = 0; p < 17; ++p) {
                int spi = __builtin_amdgcn_readlane(__builtin_bit_cast(int, s), p);
                cand[p] = __builtin_bit_cast(float, spi) + T[p];
            }
            float t0 = max3f(cand[0],  cand[1],  cand[2]);
            float t1 = max3f(cand[3],  cand[4],  cand[5]);
            float t2 = max3f(cand[6],  cand[7],  cand[8]);
            float t3 = max3f(cand[9],  cand[10], cand[11]);
            float t4 = max3f(cand[12], cand[13], cand[14]);
            float u0 = max3f(t0, t1, t2);
            float u1 = max3f(t3, t4, cand[15]);
            float mx = max3f(u0, u1, cand[16]);

            // first-match argmax (reference tie-break: smallest p)
            int arg = 16;
#pragma unroll
            for (int p = 15; p >= 0; --p) arg = (cand[p] == mx) ? p : arg;

            float a = mx + e;
            s = mv ? a : s;            // exact: mask is 0.0f or 1.0f
            if (lane < CC) bp8[t * ES + lane] = (unsigned char)arg;

            e = e_n; mv = mv_n;
        }

        float fin = s + Tstop;
        if (lane < CC) fbuf[lane] = fin;
    }
    __syncthreads();

    // ---- final argmax + segment transfer tables (wave 0) ----
    if (tid < 64) {
        const int lane = tid;

        float best = fbuf[0];
        int   btag = 0;
#pragma unroll
        for (int c = 1; c < CC; ++c) {
            float v = fbuf[c];
            if (v > best) { best = v; btag = c; }
        }
        if (lane == 0) out[b] = best;
        // stash btag for the vseg phase via lane0's later use (recomputed there)

        // segment transfer tables: lane i covers t in [i*8, i*8+8)
        const int base = lane * 8;
        float mj[8];
#pragma unroll
        for (int j = 0; j < 8; ++j) mj[j] = mlds[base + j];
#pragma unroll
        for (int c = 0; c < CC; ++c) {
            int x = c;
#pragma unroll
            for (int j = 7; j >= 0; --j) {
                int nx = bp8[(base + j) * ES + x];
                x = (mj[j] > 0.0f) ? nx : x;
            }
            Hl[lane * ES + c] = (unsigned char)x;
        }
    }
    __syncthreads();

    // ---- scalar chain of segment-entry values (lane 0) ----
    if (tid == 0) {
        float best = fbuf[0];
        int   btag = 0;
#pragma unroll
        for (int c = 1; c < CC; ++c) {
            float v = fbuf[c];
            if (v > best) { best = v; btag = c; }
        }
        int v = btag;
        vseg[63] = (unsigned char)v;
        for (int i = 62; i >= 0; --i) {
            v = Hl[(i + 1) * ES + v];
            vseg[i] = (unsigned char)v;
        }
    }
    __syncthreads();

    // ---- fill 8 tags per lane, store as 2x float4 (wave 0) ----
    if (tid < 64) {
        const int lane = tid;
        const int base = lane * 8;
        int cur = vseg[lane];
        float tg[8];
#pragma unroll
        for (int j = 7; j >= 0; --j) {
            bool valid = mlds[base + j] > 0.0f;
            tg[j] = (float)(valid ? cur : -1);
            int nx = bp8[(base + j) * ES + cur];
            cur = valid ? nx : cur;
        }
        float4* pout = reinterpret_cast<float4*>(out + BB + (size_t)b * LL + base);
        pout[0] = make_float4(tg[0], tg[1], tg[2], tg[3]);
        pout[1] = make_float4(tg[4], tg[5], tg[6], tg[7]);
    }
}

extern "C" void kernel_launch(void* const* d_in, const int* in_sizes, int n_in,
                              void* d_out, int out_size, void* d_ws, size_t ws_size,
                              hipStream_t stream) {
    const float* feats = (const float*)d_in[0];
    const float* masks = (const float*)d_in[1];
    const float* W     = (const float*)d_in[2];
    const float* bias  = (const float*)d_in[3];
    const float* trans = (const float*)d_in[4];
    float* out = (float*)d_out;
    (void)d_ws; (void)ws_size;   // workspace-free: emissions live in LDS

    crf_fused<<<dim3(BB), dim3(256), 0, stream>>>(feats, masks, W, bias, trans, out);
}